// Round 6
// baseline (1353.701 us; speedup 1.0000x reference)
//
#include <hip/hip_runtime.h>

#define D      128
#define NINIT  100000
#define LVLS   64
#define M      4096
#define NRULES 256
#define NTOT   (NINIT + LVLS * M)
#define NBLK   256
#define BLOCK  512
#define TILE   16
#define GRP    (NBLK / 8)   // 32 blocks per barrier group

typedef __attribute__((ext_vector_type(8))) short short8;   // 8 bf16 = 4 VGPRs
typedef __attribute__((ext_vector_type(4))) float floatx4;  // MFMA accumulator

__device__ __forceinline__ unsigned short f2bf(float x) {  // RNE fp32->bf16
  unsigned u = __float_as_uint(x);
  u += 0x7fffu + ((u >> 16) & 1u);
  return (unsigned short)(u >> 16);
}

// ---------------------------------------------------------------------------
// ws layout (bytes):
//   4096*g  (g=0..7)  : xcnt[g]  (group arrive counters, separate pages)
//   4096*(8+g)        : xgen[g]  (group release flags, separate pages)
//   4096*16           : gcnt; +256: ggen
//   4096*17           : sums[2] fp32
//   HDR               : store bf16 [NTOT][128]
//   WF_OFF            : Wfrag bf16 [NRULES][32768] frag-linear
//   SI_OFF            : sorted_idx  int [LVLS][M]
//   SR_OFF            : sorted_rule int [LVLS][M]
// ---------------------------------------------------------------------------
#define HDR    (4096 * 18)
#define WF_OFF ((size_t)HDR + (size_t)NTOT * D * 2)
#define SI_OFF (WF_OFF + (size_t)NRULES * 2 * D * D * 2)
#define SR_OFF (SI_OFF + (size_t)LVLS * M * 4)

// Hierarchical grid barrier: 32 arrivals per group line (8 pages), 8 leaders
// on one global line. Relaxed polls + one acquire fence on exit (no per-poll
// L1 invalidate). s_sleep backoff.
__device__ __forceinline__ void grid_sync(char* ws, unsigned target) {
  __syncthreads();
  if (threadIdx.x == 0) {
    const unsigned g = blockIdx.x & 7u;
    unsigned* xcnt = (unsigned*)(ws + 4096 * g);
    unsigned* xgen = (unsigned*)(ws + 4096 * (8 + g));
    unsigned* gcnt = (unsigned*)(ws + 4096 * 16);
    unsigned* ggen = (unsigned*)(ws + 4096 * 16 + 256);
    if (__hip_atomic_fetch_add(xcnt, 1u, __ATOMIC_ACQ_REL,
                               __HIP_MEMORY_SCOPE_AGENT) == GRP - 1) {
      // group leader
      if (__hip_atomic_fetch_add(gcnt, 1u, __ATOMIC_ACQ_REL,
                                 __HIP_MEMORY_SCOPE_AGENT) == 7) {
        __hip_atomic_store(gcnt, 0u, __ATOMIC_RELAXED, __HIP_MEMORY_SCOPE_AGENT);
        __hip_atomic_store(ggen, target, __ATOMIC_RELEASE, __HIP_MEMORY_SCOPE_AGENT);
      } else {
        while (__hip_atomic_load(ggen, __ATOMIC_RELAXED,
                                 __HIP_MEMORY_SCOPE_AGENT) < target)
          __builtin_amdgcn_s_sleep(2);
        __builtin_amdgcn_fence(__ATOMIC_ACQUIRE, "agent");
      }
      __hip_atomic_store(xcnt, 0u, __ATOMIC_RELAXED, __HIP_MEMORY_SCOPE_AGENT);
      __hip_atomic_store(xgen, target, __ATOMIC_RELEASE, __HIP_MEMORY_SCOPE_AGENT);
    } else {
      while (__hip_atomic_load(xgen, __ATOMIC_RELAXED,
                               __HIP_MEMORY_SCOPE_AGENT) < target)
        __builtin_amdgcn_s_sleep(8);
      __builtin_amdgcn_fence(__ATOMIC_ACQUIRE, "agent");
    }
  }
  __syncthreads();
}

__device__ __forceinline__ float softplusf(float x) {
  return fmaxf(x, 0.f) + log1pf(expf(-fabsf(x)));
}

__global__ __launch_bounds__(BLOCK, 2) void fused_kernel(
    const float* __restrict__ thax_table, const float* __restrict__ sine_table,
    const float* __restrict__ rule_W, const float* __restrict__ rule_b,
    const float* __restrict__ eval_w, const float* __restrict__ eval_b,
    const float* __restrict__ pos_vals, const float* __restrict__ neg_vals,
    const int* __restrict__ init_thax, const int* __restrict__ init_sine,
    const int* __restrict__ parents, const int* __restrict__ rules,
    float* __restrict__ out, char* __restrict__ ws) {
  __shared__ __align__(16) char smem[16 * 264 * 2];  // pe tile / sort scratch
  __shared__ int s_sid[2][TILE];
  __shared__ int s_rule[2][TILE];
  __shared__ float sred[16];

  float* sums = (float*)(ws + 4096 * 17);
  unsigned short* store = (unsigned short*)(ws + HDR);
  unsigned short* Wfrag = (unsigned short*)(ws + WF_OFF);
  int* sorted_idx = (int*)(ws + SI_OFF);
  int* sorted_rule = (int*)(ws + SR_OFF);

  const int tid = threadIdx.x, b = blockIdx.x;
  const int wave = tid >> 6, lane = tid & 63;
  const int col = (wave << 4) + (lane & 15);

  // ---- pre A: weight frags for rule b -> Wfrag (frag-linear bf16) ----
  {
    const float* Wr = rule_W + (size_t)b * (2 * D * D);
    unsigned short* outw = Wfrag + (size_t)b * (2 * D * D);
    for (int f = wave; f < 64; f += 8) {
      int ks = f >> 3, ct = f & 7;
      int krow = ks * 32 + (lane >> 4) * 8;
      int c2 = ct * 16 + (lane & 15);
      unsigned short v[8];
#pragma unroll
      for (int q = 0; q < 8; ++q) v[q] = f2bf(Wr[(size_t)(krow + q) * D + c2]);
      uint4 pk;
      pk.x = (unsigned)v[0] | ((unsigned)v[1] << 16);
      pk.y = (unsigned)v[2] | ((unsigned)v[3] << 16);
      pk.z = (unsigned)v[4] | ((unsigned)v[5] << 16);
      pk.w = (unsigned)v[6] | ((unsigned)v[7] << 16);
      *(uint4*)(outw + ((size_t)f * 64 + lane) * 8) = pk;
    }
  }

  // ---- pre B: counting-sort by rule (blocks 0..63, level = b) ----
  if (b < LVLS) {
    int* cnt = (int*)smem;
    int* base = cnt + NRULES;
    const int* rl = rules + (size_t)b * M;
    if (tid < NRULES) cnt[tid] = 0;
    __syncthreads();
    for (int m = tid; m < M; m += BLOCK) atomicAdd(&cnt[rl[m]], 1);
    __syncthreads();
    if (tid == 0) {
      int run = 0;
      for (int q = 0; q < NRULES; ++q) { base[q] = run; run += cnt[q]; }
    }
    __syncthreads();
    if (tid < NRULES) cnt[tid] = base[tid];
    __syncthreads();
    for (int m = tid; m < M; m += BLOCK) {
      int r = rl[m];
      int p = atomicAdd(&cnt[r], 1);
      sorted_idx[(size_t)b * M + p] = m;
      sorted_rule[(size_t)b * M + p] = r;
    }
  }

  // ---- pre C: init embeddings (grid-stride) ----
  for (int idx = b * BLOCK + tid; idx < NINIT * 16; idx += NBLK * BLOCK) {
    int node = idx >> 4, sg = idx & 15;
    const float4* t = (const float4*)(thax_table + (size_t)init_thax[node] * D) + sg * 2;
    const float4* s = (const float4*)(sine_table + (size_t)init_sine[node] * D) + sg * 2;
    float4 a0 = t[0], a1 = t[1], b0 = s[0], b1 = s[1];
    float v[8] = {a0.x + b0.x, a0.y + b0.y, a0.z + b0.z, a0.w + b0.w,
                  a1.x + b1.x, a1.y + b1.y, a1.z + b1.z, a1.w + b1.w};
    uint4 pk;
    pk.x = (unsigned)f2bf(v[0]) | ((unsigned)f2bf(v[1]) << 16);
    pk.y = (unsigned)f2bf(v[2]) | ((unsigned)f2bf(v[3]) << 16);
    pk.z = (unsigned)f2bf(v[4]) | ((unsigned)f2bf(v[5]) << 16);
    pk.w = (unsigned)f2bf(v[6]) | ((unsigned)f2bf(v[7]) << 16);
    *(uint4*)(store + (size_t)node * D + sg * 8) = pk;
  }

  // ---- pre D: pos/neg sums ----
  {
    float sp = 0.f, sn = 0.f;
    for (int i = b * BLOCK + tid; i < NTOT; i += NBLK * BLOCK) {
      sp += pos_vals[i];
      sn += neg_vals[i];
    }
    for (int m = 32; m; m >>= 1) {
      sp += __shfl_xor(sp, m, 64);
      sn += __shfl_xor(sn, m, 64);
    }
    __syncthreads();  // sort scratch done
    if (lane == 0) { sred[wave * 2] = sp; sred[wave * 2 + 1] = sn; }
    __syncthreads();
    if (tid == 0) {
      float tp = 0.f, tn = 0.f;
      for (int w = 0; w < 8; ++w) { tp += sred[w * 2]; tn += sred[w * 2 + 1]; }
      atomicAdd(&sums[0], tp);
      atomicAdd(&sums[1], tn);
    }
  }

  unsigned gen = 0;
  grid_sync(ws, ++gen);  // pre-phase visible everywhere

  // ---- level loop: block b owns sorted tile b of every level ----
  unsigned short* pe = (unsigned short*)smem;  // [16][264] padded rows
  const int j = tid >> 5, seg = tid & 31;      // staging role
  int my_par;
  {  // metadata for level 0 (post-barrier: sort results now visible)
    int sid = sorted_idx[b * TILE + j];
    my_par = parents[sid * 2 + (seg >> 4)];
    if (tid < TILE) s_sid[0][tid] = sorted_idx[b * TILE + tid];
    if (tid >= TILE && tid < 2 * TILE)
      s_rule[0][tid - TILE] = sorted_rule[b * TILE + (tid - TILE)];
  }
  int r0 = sorted_rule[b * TILE];
  short8 bf[8];
#pragma unroll
  for (int ks = 0; ks < 8; ++ks)
    bf[ks] = *(const short8*)(Wfrag + (size_t)r0 * (2 * D * D) +
                              (((size_t)ks * 8 + wave) * 64 + lane) * 8);
  float bias = rule_b[r0 * D + col];

  for (int l = 0; l < LVLS; ++l) {
    const int cur = l & 1;
    const int ln = (l + 1 < LVLS) ? l + 1 : 0;  // l=63: harmless dummy prefetch

    // gather: ONE dependent load (my_par prefetched last iter)
    {
      uint4 d = *(const uint4*)(store + (size_t)my_par * D + (seg & 15) * 8);
      *(uint4*)(pe + j * 264 + seg * 8) = d;
    }
    // prefetch next-level metadata (barrier-independent)
    int nsid = sorted_idx[(size_t)ln * M + b * TILE + j];
    int npar = parents[(size_t)ln * M * 2 + nsid * 2 + (seg >> 4)];
    if (tid < TILE) s_sid[cur ^ 1][tid] = sorted_idx[(size_t)ln * M + b * TILE + tid];
    if (tid >= TILE && tid < 2 * TILE)
      s_rule[cur ^ 1][tid - TILE] = sorted_rule[(size_t)ln * M + b * TILE + (tid - TILE)];
    int nrule0 = sorted_rule[(size_t)ln * M + b * TILE];
    __syncthreads();

    // compute spans (bf holds frags of s_rule[cur][0])
    const int n_base = NINIT + l * M;
    int cur_rule = s_rule[cur][0];
    int j0 = 0;
    while (j0 < TILE) {
      int r = s_rule[cur][j0];
      int e = j0 + 1;
      while (e < TILE && s_rule[cur][e] == r) ++e;
      if (r != cur_rule) {
#pragma unroll
        for (int ks = 0; ks < 8; ++ks)
          bf[ks] = *(const short8*)(Wfrag + (size_t)r * (2 * D * D) +
                                    (((size_t)ks * 8 + wave) * 64 + lane) * 8);
        bias = rule_b[r * D + col];
        cur_rule = r;
      }
      floatx4 acc = {0.f, 0.f, 0.f, 0.f};
#pragma unroll
      for (int ks = 0; ks < 8; ++ks) {
        short8 a = *(const short8*)(pe + (lane & 15) * 264 + ks * 32 +
                                    (lane >> 4) * 8);
        acc = __builtin_amdgcn_mfma_f32_16x16x32_bf16(a, bf[ks], acc, 0, 0, 0);
      }
#pragma unroll
      for (int reg = 0; reg < 4; ++reg) {
        int row = (lane >> 4) * 4 + reg;
        if (row >= j0 && row < e) {
          float v = acc[reg] + bias;
          store[(size_t)(n_base + s_sid[cur][row]) * D + col] =
              f2bf(v > 0.f ? v : 0.f);
        }
      }
      j0 = e;
    }

    // prefetch next level's span-0 frags + bias (overlaps barrier wait)
#pragma unroll
    for (int ks = 0; ks < 8; ++ks)
      bf[ks] = *(const short8*)(Wfrag + (size_t)nrule0 * (2 * D * D) +
                                (((size_t)ks * 8 + wave) * 64 + lane) * 8);
    bias = rule_b[nrule0 * D + col];
    my_par = npar;

    grid_sync(ws, ++gen);  // level l visible
  }

  // ---- loss phase ----
  {
    float a_loss = 0.f, a_pos = 0.f, a_neg = 0.f;
    const float pw = sums[1] / sums[0];
    const float eb = eval_b[0];
    const float4* wv = (const float4*)eval_w;

    for (int node = b * BLOCK + tid; node < NTOT; node += NBLK * BLOCK) {
      const uint4* v = (const uint4*)(store + (size_t)node * D);
      float dot = 0.f;
#pragma unroll
      for (int k = 0; k < 16; ++k) {
        uint4 u = v[k];
        float4 w0 = wv[k * 2], w1 = wv[k * 2 + 1];
        dot += __uint_as_float(u.x << 16) * w0.x +
               __uint_as_float(u.x & 0xffff0000u) * w0.y +
               __uint_as_float(u.y << 16) * w0.z +
               __uint_as_float(u.y & 0xffff0000u) * w0.w +
               __uint_as_float(u.z << 16) * w1.x +
               __uint_as_float(u.z & 0xffff0000u) * w1.y +
               __uint_as_float(u.w << 16) * w1.z +
               __uint_as_float(u.w & 0xffff0000u) * w1.w;
      }
      float logit = dot + eb;
      float p = pos_vals[node], n = neg_vals[node];
      float tot = p + n, y = p / tot;
      a_loss += tot * (pw * y * softplusf(-logit) + (1.f - y) * softplusf(logit));
      if (logit >= 0.f) a_pos += p; else a_neg += n;
    }
    for (int m = 32; m; m >>= 1) {
      a_loss += __shfl_xor(a_loss, m, 64);
      a_pos  += __shfl_xor(a_pos,  m, 64);
      a_neg  += __shfl_xor(a_neg,  m, 64);
    }
    float* racc = (float*)smem;  // safe: final grid_sync passed
    if (tid == 0) { racc[0] = 0.f; racc[1] = 0.f; racc[2] = 0.f; }
    __syncthreads();
    if (lane == 0) {
      atomicAdd(&racc[0], a_loss);
      atomicAdd(&racc[1], a_pos);
      atomicAdd(&racc[2], a_neg);
    }
    __syncthreads();
    if (tid == 0) {
      atomicAdd(&out[0], racc[0]);
      atomicAdd(&out[1], racc[1]);
      atomicAdd(&out[2], racc[2]);
    }
  }
}

extern "C" void kernel_launch(void* const* d_in, const int* in_sizes, int n_in,
                              void* d_out, int out_size, void* d_ws, size_t ws_size,
                              hipStream_t stream) {
  const float* thax_table = (const float*)d_in[0];
  const float* sine_table = (const float*)d_in[1];
  const float* rule_W     = (const float*)d_in[2];
  const float* rule_b     = (const float*)d_in[3];
  const float* eval_w     = (const float*)d_in[4];
  const float* eval_b     = (const float*)d_in[5];
  const float* pos_vals   = (const float*)d_in[6];
  const float* neg_vals   = (const float*)d_in[7];
  const int*   init_thax  = (const int*)d_in[8];
  const int*   init_sine  = (const int*)d_in[9];
  const int*   parents    = (const int*)d_in[10];
  const int*   rules      = (const int*)d_in[11];

  hipMemsetAsync(d_out, 0, 3 * sizeof(float), stream);
  hipMemsetAsync(d_ws, 0, HDR, stream);  // barrier pages + sums

  fused_kernel<<<NBLK, BLOCK, 0, stream>>>(
      thax_table, sine_table, rule_W, rule_b, eval_w, eval_b,
      pos_vals, neg_vals, init_thax, init_sine, parents, rules,
      (float*)d_out, (char*)d_ws);
}